// Round 5
// baseline (510.550 us; speedup 1.0000x reference)
//
#include <hip/hip_runtime.h>
#include <hip/hip_bf16.h>
#include <cstdint>
#include <cstddef>

// ---------------------------------------------------------------------------
// SelfAttentionV1: out = softmax((x Wq^T)(x Wk^T)^T / 32) (x Wv^T)
// N=8192, D=1024. Round 5: m201-style 8-phase GEMM (BK=64, dbuf-2, quadrant
// phases, counted vmcnt, cross-tile A prefetch) + nontemporal S stores.
// ---------------------------------------------------------------------------

typedef __attribute__((ext_vector_type(8))) short short8;     // bf16x8 MFMA frag
typedef __attribute__((ext_vector_type(8))) unsigned short ushort8;
typedef __attribute__((ext_vector_type(4))) float f32x4;

#define FENCE asm volatile("" ::: "memory")
__device__ __forceinline__ void wgbar() {
  FENCE; __builtin_amdgcn_s_barrier(); FENCE;
}

__device__ __forceinline__ unsigned short f2bf(float f) {
  unsigned u = __float_as_uint(f);
  u += 0x7fffu + ((u >> 16) & 1u);      // round-to-nearest-even
  return (unsigned short)(u >> 16);
}
__device__ __forceinline__ float bf2f(unsigned short h) {
  return __uint_as_float(((unsigned)h) << 16);
}

// async global->LDS, 16 bytes per lane (wave-uniform LDS base + lane*16)
__device__ __forceinline__ void glds16(const void* g, void* l) {
  __builtin_amdgcn_global_load_lds((__attribute__((address_space(1))) void*)g,
                                   (__attribute__((address_space(3))) void*)l,
                                   16, 0, 0);
}

// ---- fp32 -> bf16 cast, 8 elems/thread ----
__global__ __launch_bounds__(256) void cast_kernel(const float* __restrict__ in,
                                                   unsigned short* __restrict__ out,
                                                   int n8) {
  int i = blockIdx.x * 256 + threadIdx.x;
  if (i >= n8) return;
  const f32x4* in4 = (const f32x4*)in;
  f32x4 a = in4[2 * i];
  f32x4 b = in4[2 * i + 1];
  ushort8 o;
#pragma unroll
  for (int j = 0; j < 4; ++j) o[j] = f2bf(a[j]);
#pragma unroll
  for (int j = 0; j < 4; ++j) o[4 + j] = f2bf(b[j]);
  ((ushort8*)out)[i] = o;
}

// ---------------------------------------------------------------------------
// 8-phase GEMM core: C[gm0..+256, gn0..+256] = scale * A * B^T
// A,B bf16 rows of K elems (ldab bytes). 512 thr = 8 waves (2M x 4N),
// wave-out 128x64. BK=64 (128-B K-window), double-buffered LDS (2 x 64 KiB).
// Per K-tile j: 4 phases, each {2 glds(tile j+1) | 4-8 ds_read | barrier |
// 16 MFMA (setprio) | barrier}. Counted vmcnt: 2 at p0 (B(j) landed),
// 4 at p3 (A(j+1) landed; B(j+1) stays in flight). Cross-wave safety: every
// read of freshly staged data is behind a barrier that follows all waves'
// own vmcnt. Cross-tile prefetch: A-low frags of tile j+1 read at p3(j).
// LDS tile [256 rows][128 B]; swizzle colbyte ^= (row&7)<<4 (conflict-free
// b128 reads); staging pre-swizzles the GLOBAL source, LDS dest linear.
// ---------------------------------------------------------------------------
#define QUAD(mbase, nbase, aArr, bArr)                                        \
  do {                                                                        \
    _Pragma("unroll") for (int m_ = 0; m_ < 4; ++m_)                          \
    _Pragma("unroll") for (int n_ = 0; n_ < 2; ++n_)                          \
    _Pragma("unroll") for (int k_ = 0; k_ < 2; ++k_)                          \
      acc[(mbase) + m_][(nbase) + n_] =                                       \
        __builtin_amdgcn_mfma_f32_16x16x32_bf16(aArr[m_][k_], bArr[n_][k_],   \
          acc[(mbase) + m_][(nbase) + n_], 0, 0, 0);                          \
  } while (0)

template <typename OutT, bool NTS>
__device__ __forceinline__ void gemm_core(
    const unsigned short* __restrict__ A, const unsigned short* __restrict__ B,
    OutT* __restrict__ C, int ldc, size_t ldab /*row bytes*/, int NT2,
    int gm0, int gn0, float scale, char* lds) {
  const int tid = threadIdx.x;
  const int lane = tid & 63, w = tid >> 6;
  const int wm = w >> 2, wn = w & 3;            // 2M x 4N wave grid

  // LDS: buf b: A at b*65536, B at b*65536+32768 (each 256 rows x 128 B)
  char* const A0b = lds;
  char* const B0b = lds + 32768;
  char* const A1b = lds + 65536;
  char* const B1b = lds + 65536 + 32768;

  // ---- staging (writer): thread t covers row (t>>3), 16-B slot (t&7) of an
  // 8 KB line (64 rows). Source col pre-swizzled: ^ ((row&7)<<4).
  const size_t off64 = (size_t)64 * ldab;
  const int scol = (((tid & 7) ^ ((tid >> 3) & 7)) << 4);
  const char* pAs = (const char*)A + (size_t)(gm0 + (tid >> 3)) * ldab + scol;
  const char* pBs = (const char*)B + (size_t)(gn0 + (tid >> 3)) * ldab + scol;
  const int dstw = w * 1024;

  // ---- reader: frag addr = buf + base + mi*2048 + kcol[kk],
  // kcol = (kk*64 + (lane>>4)*16) ^ ((lane&7)<<4)
  const int aRd = wm * 16384 + (lane & 15) * 128;
  const int bRd = wn * 8192 + (lane & 15) * 128;
  const int kc0 = (((lane >> 4) << 4) ^ ((lane & 7) << 4));
  const int kc1 = kc0 ^ 64;

  f32x4 acc[8][4];
#pragma unroll
  for (int m = 0; m < 8; ++m)
#pragma unroll
    for (int n = 0; n < 4; ++n) acc[m][n] = (f32x4)(0.0f);

  short8 aLo[4][2], aHi[4][2], bLo[2][2], bHi[2][2];

  // ---- prologue: stage tile 0 (A calls 0-3 then B calls 0-3)
#pragma unroll
  for (int c = 0; c < 4; ++c) glds16(pAs + c * off64, A0b + c * 8192 + dstw);
#pragma unroll
  for (int c = 0; c < 4; ++c) glds16(pBs + c * off64, B0b + c * 8192 + dstw);
  asm volatile("s_waitcnt vmcnt(4)" ::: "memory");  // A(0) landed (own)
  wgbar();                                          // ... and all waves'
  // pre-read A-low frags of tile 0
#pragma unroll
  for (int m = 0; m < 4; ++m) {
    aLo[m][0] = *(const short8*)(A0b + aRd + m * 2048 + kc0);
    aLo[m][1] = *(const short8*)(A0b + aRd + m * 2048 + kc1);
  }

  const char* sA = pAs + 128;   // stage ptr for tile j+1 (K advances 128 B)
  const char* sB = pBs + 128;

  for (int j = 0; j < NT2; ++j) {
    const int par = j & 1;
    const char* Ab = par ? A1b : A0b;
    const char* Bb = par ? B1b : B0b;
    char* An = par ? A0b : A1b;
    char* Bn = par ? B0b : B1b;
    const bool stg = (j + 1 < NT2);

    // ================= phase 0: Q0 = mi0-3 x ni0-1 =================
    if (stg) {
      glds16(sA, An + dstw);
      glds16(sA + off64, An + 8192 + dstw);
    }
    if (stg) asm volatile("s_waitcnt vmcnt(2)" ::: "memory");  // B(j) landed
    else     asm volatile("s_waitcnt vmcnt(0)" ::: "memory");
    wgbar();                                   // all waves' B(j) visible
#pragma unroll
    for (int n = 0; n < 2; ++n) {
      bLo[n][0] = *(const short8*)(Bb + bRd + n * 2048 + kc0);
      bLo[n][1] = *(const short8*)(Bb + bRd + n * 2048 + kc1);
    }
    __builtin_amdgcn_s_setprio(1);
    QUAD(0, 0, aLo, bLo);
    __builtin_amdgcn_s_setprio(0);
    wgbar();

    // ================= phase 1: Q1 = mi0-3 x ni2-3 =================
    if (stg) {
      glds16(sA + 2 * off64, An + 16384 + dstw);
      glds16(sA + 3 * off64, An + 24576 + dstw);
    }
#pragma unroll
    for (int n = 0; n < 2; ++n) {
      bHi[n][0] = *(const short8*)(Bb + bRd + (2 + n) * 2048 + kc0);
      bHi[n][1] = *(const short8*)(Bb + bRd + (2 + n) * 2048 + kc1);
    }
    wgbar();
    __builtin_amdgcn_s_setprio(1);
    QUAD(0, 2, aLo, bHi);
    __builtin_amdgcn_s_setprio(0);
    wgbar();

    // ================= phase 2: Q2 = mi4-7 x ni2-3 =================
    if (stg) {
      glds16(sB, Bn + dstw);
      glds16(sB + off64, Bn + 8192 + dstw);
    }
#pragma unroll
    for (int m = 0; m < 4; ++m) {
      aHi[m][0] = *(const short8*)(Ab + aRd + (4 + m) * 2048 + kc0);
      aHi[m][1] = *(const short8*)(Ab + aRd + (4 + m) * 2048 + kc1);
    }
    wgbar();
    __builtin_amdgcn_s_setprio(1);
    QUAD(4, 2, aHi, bHi);
    __builtin_amdgcn_s_setprio(0);
    wgbar();

    // ================= phase 3: Q3 = mi4-7 x ni0-1 =================
    if (stg) {
      glds16(sB + 2 * off64, Bn + 16384 + dstw);
      glds16(sB + 3 * off64, Bn + 24576 + dstw);
      asm volatile("s_waitcnt vmcnt(4)" ::: "memory");  // A(j+1) landed
    }
    wgbar();                                   // all waves' A(j+1) visible
    if (stg) {
      // cross-tile prefetch: A-low frags of tile j+1 (aLo regs dead)
#pragma unroll
      for (int m = 0; m < 4; ++m) {
        aLo[m][0] = *(const short8*)(An + aRd + m * 2048 + kc0);
        aLo[m][1] = *(const short8*)(An + aRd + m * 2048 + kc1);
      }
    }
    __builtin_amdgcn_s_setprio(1);
    QUAD(4, 0, aHi, bLo);
    __builtin_amdgcn_s_setprio(0);
    wgbar();

    sA += 128; sB += 128;
  }

  // ---- epilogue: C row=(lane>>4)*4+jj, col=lane&15 (m89-verified layout)
  const int r0 = gm0 + wm * 128 + ((lane >> 4) << 2);
  const int c0 = gn0 + wn * 64 + (lane & 15);
#pragma unroll
  for (int mi = 0; mi < 8; ++mi) {
#pragma unroll
    for (int ni = 0; ni < 4; ++ni) {
      f32x4 v = acc[mi][ni];
#pragma unroll
      for (int jj = 0; jj < 4; ++jj) {
        float val = v[jj] * scale;
        size_t idx = (size_t)(r0 + mi * 16 + jj) * ldc + (c0 + ni * 16);
        if (sizeof(OutT) == 2) {
          unsigned short hv = f2bf(val);
          if (NTS) __builtin_nontemporal_store(hv, (unsigned short*)C + idx);
          else     ((unsigned short*)C)[idx] = hv;
        } else {
          ((float*)C)[idx] = val;
        }
      }
    }
  }
}

// bijective XCD chunking: consecutive logical blocks land on the same XCD
__device__ __forceinline__ void swz_block(int& bx, int& by, int& bz) {
  const int gx = gridDim.x, gy = gridDim.y;
  const int f = (blockIdx.z * gy + blockIdx.y) * gx + blockIdx.x;
  const int nwg = gx * gy * gridDim.z;      // all grids are multiples of 8
  const int q = nwg >> 3;
  const int l = (f & 7) * q + (f >> 3);
  bx = l % gx;
  const int r = l / gx;
  by = r % gy;
  bz = r / gy;
}

__global__ __launch_bounds__(512, 2) void gemm_s_kernel(
    const unsigned short* __restrict__ Q, const unsigned short* __restrict__ Kh,
    unsigned short* __restrict__ S) {
  __shared__ char lds[131072];
  int bx, by, bz; swz_block(bx, by, bz);
  gemm_core<unsigned short, true>(Q, Kh, S, 8192, 2048, 16, by * 256, bx * 256,
                                  0.03125f, lds);
}

__global__ __launch_bounds__(512, 2) void gemm_qkv_kernel(
    const unsigned short* __restrict__ X,
    const unsigned short* __restrict__ Wq, const unsigned short* __restrict__ Wk,
    const unsigned short* __restrict__ Wv,
    unsigned short* __restrict__ Qo, unsigned short* __restrict__ Ko,
    unsigned short* __restrict__ Vo) {
  __shared__ char lds[131072];
  int bx, by, bz; swz_block(bx, by, bz);
  const unsigned short* B = (bz == 0) ? Wq : (bz == 1) ? Wk : Wv;
  unsigned short* C = (bz == 0) ? Qo : (bz == 1) ? Ko : Vo;
  gemm_core<unsigned short, false>(X, B, C, 1024, 2048, 16, by * 256, bx * 256,
                                   1.0f, lds);
}

// PV with split-K x2: z=0 writes d_out, z=1 writes partial buffer
__global__ __launch_bounds__(512, 2) void gemm_pv_kernel(
    const unsigned short* __restrict__ S, const unsigned short* __restrict__ Vt,
    float* __restrict__ O, float* __restrict__ P1) {
  __shared__ char lds[131072];
  int bx, by, bz; swz_block(bx, by, bz);
  const unsigned short* A = S + (size_t)bz * 4096;   // k-offset 4096 elems
  const unsigned short* B = Vt + (size_t)bz * 4096;
  float* C = bz ? P1 : O;
  gemm_core<float, false>(A, B, C, 1024, 16384, 64, by * 256, bx * 256,
                          1.0f, lds);
}

__global__ __launch_bounds__(256) void add_kernel(float* __restrict__ out,
                                                  const float* __restrict__ p,
                                                  int n4) {
  int i = blockIdx.x * 256 + threadIdx.x;
  if (i < n4) {
    f32x4 a = ((const f32x4*)out)[i];
    f32x4 b = ((const f32x4*)p)[i];
    ((f32x4*)out)[i] = a + b;
  }
}

// ---- row softmax in place over bf16 S, ncol = 8192 (256 thr x 32 elems) ----
__global__ __launch_bounds__(256) void softmax_kernel(unsigned short* __restrict__ S,
                                                      int ncol) {
  const int t = threadIdx.x;
  unsigned short* rp = S + (size_t)blockIdx.x * ncol;
  ushort8* rv = (ushort8*)rp;
  float f[32];
#pragma unroll
  for (int c = 0; c < 4; ++c) {
    ushort8 v = rv[c * 256 + t];
#pragma unroll
    for (int j = 0; j < 8; ++j) f[c * 8 + j] = bf2f(v[j]);
  }
  float m = -1e30f;
#pragma unroll
  for (int i = 0; i < 32; ++i) m = fmaxf(m, f[i]);
#pragma unroll
  for (int o = 32; o; o >>= 1) m = fmaxf(m, __shfl_xor(m, o));
  __shared__ float red[8];
  if ((t & 63) == 0) red[t >> 6] = m;
  __syncthreads();
  m = fmaxf(fmaxf(red[0], red[1]), fmaxf(red[2], red[3]));

  float s = 0.0f;
#pragma unroll
  for (int i = 0; i < 32; ++i) {
    f[i] = __expf(f[i] - m);
    s += f[i];
  }
#pragma unroll
  for (int o = 32; o; o >>= 1) s += __shfl_xor(s, o);
  if ((t & 63) == 0) red[4 + (t >> 6)] = s;
  __syncthreads();
  s = red[4] + red[5] + red[6] + red[7];
  float inv = 1.0f / s;
#pragma unroll
  for (int c = 0; c < 4; ++c) {
    ushort8 v;
#pragma unroll
    for (int j = 0; j < 8; ++j) v[j] = f2bf(f[c * 8 + j] * inv);
    rv[c * 256 + t] = v;
  }
}

// ---- 64x64 tiled transpose: out[C][R] = in[R][C] (bf16) ----
__global__ __launch_bounds__(256) void transpose_kernel(
    const unsigned short* __restrict__ in, unsigned short* __restrict__ out,
    int R, int Ccols) {
  __shared__ unsigned short tile[64][65];
  const int tx = threadIdx.x & 63, ty = threadIdx.x >> 6;
  const int r0 = blockIdx.y * 64, c0 = blockIdx.x * 64;
#pragma unroll
  for (int i = 0; i < 16; ++i) {
    int r = ty * 16 + i;
    tile[r][tx] = in[(size_t)(r0 + r) * Ccols + c0 + tx];
  }
  __syncthreads();
#pragma unroll
  for (int i = 0; i < 16; ++i) {
    int r = ty * 16 + i;
    out[(size_t)(c0 + r) * R + r0 + tx] = tile[tx][r];
  }
}

extern "C" void kernel_launch(void* const* d_in, const int* in_sizes, int n_in,
                              void* d_out, int out_size, void* d_ws, size_t ws_size,
                              hipStream_t stream) {
  (void)in_sizes; (void)n_in; (void)out_size; (void)ws_size;
  const int N = 8192, D = 1024;
  const float* x  = (const float*)d_in[0];
  const float* Wq = (const float*)d_in[1];
  const float* Wk = (const float*)d_in[2];
  const float* Wv = (const float*)d_in[3];
  float* out = (float*)d_out;

  char* ws = (char*)d_ws;
  size_t off = 0;
  auto alloc = [&](size_t bytes) { char* p = ws + off; off += bytes; return p; };
  unsigned short* xh  = (unsigned short*)alloc((size_t)N * D * 2);  // 16.8 MB
  unsigned short* Wqh = (unsigned short*)alloc((size_t)D * D * 2);  // 2 MB
  unsigned short* Wkh = (unsigned short*)alloc((size_t)D * D * 2);
  unsigned short* Wvh = (unsigned short*)alloc((size_t)D * D * 2);
  unsigned short* Qh  = (unsigned short*)alloc((size_t)N * D * 2);  // 16.8 MB
  unsigned short* Kh  = (unsigned short*)alloc((size_t)N * D * 2);
  unsigned short* Vh  = (unsigned short*)alloc((size_t)N * D * 2);
  unsigned short* S   = (unsigned short*)alloc((size_t)N * N * 2);  // 134.2 MB
  unsigned short* Vth = xh;            // xh dead after QKV
  float* Pbuf = (float*)Qh;            // Qh+Kh (33.6 MB) dead after S-GEMM

  // casts
  cast_kernel<<<(N * D / 8) / 256, 256, 0, stream>>>(x, xh, N * D / 8);
  cast_kernel<<<(D * D / 8) / 256, 256, 0, stream>>>(Wq, Wqh, D * D / 8);
  cast_kernel<<<(D * D / 8) / 256, 256, 0, stream>>>(Wk, Wkh, D * D / 8);
  cast_kernel<<<(D * D / 8) / 256, 256, 0, stream>>>(Wv, Wvh, D * D / 8);

  // Q,K,V = x @ W^T  (fused over z)
  gemm_qkv_kernel<<<dim3(4, 32, 3), 512, 0, stream>>>(xh, Wqh, Wkh, Wvh,
                                                      Qh, Kh, Vh);

  // S = Q @ K^T * (1/32)  (nontemporal S stores)
  gemm_s_kernel<<<dim3(32, 32), 512, 0, stream>>>(Qh, Kh, S);

  // softmax rows (in place)
  softmax_kernel<<<N, 256, 0, stream>>>(S, N);

  // Vt = V^T  [1024,8192]
  transpose_kernel<<<dim3(D / 64, N / 64), 256, 0, stream>>>(Vh, Vth, N, D);

  // out = P @ Vt^T  (split-K x2, full-chip grid)
  gemm_pv_kernel<<<dim3(4, 32, 2), 512, 0, stream>>>(S, Vth, out, Pbuf);

  // out += partial
  add_kernel<<<(N * D / 4) / 256, 256, 0, stream>>>(out, Pbuf, N * D / 4);
}